// Round 1
// baseline (310.034 us; speedup 1.0000x reference)
//
#include <hip/hip_runtime.h>
#include <hip/hip_bf16.h>
#include <cstdint>
#include <cstddef>

#define B_DIM 2048
#define D_DIM 512
#define NROWS 12288        // 6B rows of z
#define HALF  6144         // 3B
#define K_PROJ 1024
#define NTILE 96           // NROWS/128
#define EXP_SCALE 2.8853900817779268f   // log2(e)/TEMP, TEMP=0.5

typedef __attribute__((ext_vector_type(8))) __bf16 bf16x8;
typedef __attribute__((ext_vector_type(4))) float f32x4;

__device__ __forceinline__ unsigned short f2bf(float x) {
  __hip_bfloat16 h = __float2bfloat16(x);
  return *reinterpret_cast<unsigned short*>(&h);
}

__device__ __forceinline__ void gload_lds16(const void* g, void* l) {
  __builtin_amdgcn_global_load_lds(
      (const __attribute__((address_space(1))) unsigned int*)g,
      (__attribute__((address_space(3))) unsigned int*)l,
      16, 0, 0);
}

// ---------------- gather f -> Abig bf16 [12288 x 1024] ----------------
// row r (<HALF: f_spa, else f_seq), p=rr/B, i=rr%B, sel={0,1,3}[p]
// Abig[r][k] = k<512 ? f[i,sel,k] : f[i,2,k-512]
__global__ __launch_bounds__(256) void gather_convert(
    const float* __restrict__ f_seq, const float* __restrict__ f_spa,
    __hip_bfloat16* __restrict__ Abig) {
  int t = blockIdx.x * 256 + threadIdx.x;   // one thread per 4 elems
  int r = t >> 8;
  int k = (t & 255) << 2;
  const float* f = (r < HALF) ? f_spa : f_seq;
  int rr = (r < HALF) ? r : r - HALF;
  int p = rr >> 11;           // /2048
  int i = rr & 2047;
  int sel = (p == 2) ? 3 : p;
  const float* src;
  if (k < D_DIM) src = f + ((size_t)i * 4 + sel) * D_DIM + k;
  else           src = f + ((size_t)i * 4 + 2) * D_DIM + (k - D_DIM);
  float4 xv = *(const float4*)src;
  uint2 o;
  o.x = (unsigned int)f2bf(xv.x) | ((unsigned int)f2bf(xv.y) << 16);
  o.y = (unsigned int)f2bf(xv.z) | ((unsigned int)f2bf(xv.w) << 16);
  *(uint2*)(Abig + (size_t)r * 1024 + k) = o;
}

// ---------------- W [1024x512] -> Wt bf16 [512 x 1024] (transposed) ----
__global__ __launch_bounds__(256) void wt_convert(
    const float* __restrict__ W, __hip_bfloat16* __restrict__ Wt) {
  int t = blockIdx.x * 256 + threadIdx.x;   // per 4 elems of Wt
  int n = t >> 8;
  int k = (t & 255) << 2;
  float x0 = W[(size_t)(k + 0) * 512 + n];
  float x1 = W[(size_t)(k + 1) * 512 + n];
  float x2 = W[(size_t)(k + 2) * 512 + n];
  float x3 = W[(size_t)(k + 3) * 512 + n];
  uint2 o;
  o.x = (unsigned int)f2bf(x0) | ((unsigned int)f2bf(x1) << 16);
  o.y = (unsigned int)f2bf(x2) | ((unsigned int)f2bf(x3) << 16);
  *(uint2*)(Wt + (size_t)n * 1024 + k) = o;
}

// ---------------- shared 128x128 MFMA tile core (C = A @ B^T form) ----
// Arows/Brows: row-major bf16, both indexed by their own row (m for A, n for B),
// contiguous K. LDS tiles [128][32] linear. 4 waves in 2x2 layout.
template<int STRIDE>
__device__ __forceinline__ void gemm_tile_128(
    const __hip_bfloat16* Arows, const __hip_bfloat16* Brows, int K,
    __hip_bfloat16* As, __hip_bfloat16* Bs, f32x4 acc[4][4], int tid) {
  int w = tid >> 6, lane = tid & 63;
  int wr = w >> 1, wc = w & 1;
  int g = lane >> 4, l16 = lane & 15;
  for (int kt = 0; kt < K; kt += 32) {
    // stage A,B: 2 issues each, 16B/lane, linear LDS (granule gr -> [gr>>2][gr&3])
    {
      int gr0 = tid;        int row0 = gr0 >> 2, ch0 = gr0 & 3;
      int gr1 = 256 + tid;  int row1 = gr1 >> 2, ch1 = gr1 & 3;
      gload_lds16(Arows + (size_t)row0 * STRIDE + kt + ch0 * 8, As + w * 512);
      gload_lds16(Arows + (size_t)row1 * STRIDE + kt + ch1 * 8, As + 2048 + w * 512);
      gload_lds16(Brows + (size_t)row0 * STRIDE + kt + ch0 * 8, Bs + w * 512);
      gload_lds16(Brows + (size_t)row1 * STRIDE + kt + ch1 * 8, Bs + 2048 + w * 512);
    }
    __syncthreads();   // compiler emits vmcnt(0) drain before barrier
    bf16x8 af[4], bfr[4];
#pragma unroll
    for (int mi = 0; mi < 4; ++mi)
      af[mi] = *(const bf16x8*)(As + (wr * 64 + mi * 16 + l16) * 32 + g * 8);
#pragma unroll
    for (int ni = 0; ni < 4; ++ni)
      bfr[ni] = *(const bf16x8*)(Bs + (wc * 64 + ni * 16 + l16) * 32 + g * 8);
#pragma unroll
    for (int mi = 0; mi < 4; ++mi)
#pragma unroll
      for (int ni = 0; ni < 4; ++ni)
        acc[mi][ni] = __builtin_amdgcn_mfma_f32_16x16x32_bf16(af[mi], bfr[ni], acc[mi][ni], 0, 0, 0);
    __syncthreads();
  }
}

// ---------------- projection GEMM: v = Abig @ Wt^T + b  (fp32 out) ----
__global__ __launch_bounds__(256) void proj_gemm(
    const __hip_bfloat16* __restrict__ Abig, const __hip_bfloat16* __restrict__ Wt,
    const float* __restrict__ bvec, float* __restrict__ v) {
  __shared__ __align__(16) __hip_bfloat16 As[4096], Bs[4096];
  int bn = blockIdx.x, bm = blockIdx.y;
  f32x4 acc[4][4];
#pragma unroll
  for (int i = 0; i < 4; ++i)
#pragma unroll
    for (int j = 0; j < 4; ++j) acc[i][j] = (f32x4){0.f, 0.f, 0.f, 0.f};
  int tid = threadIdx.x;
  gemm_tile_128<1024>(Abig + (size_t)bm * 128 * 1024, Wt + (size_t)bn * 128 * 1024,
                      1024, As, Bs, acc, tid);
  int w = tid >> 6, lane = tid & 63, wr = w >> 1, wc = w & 1, g = lane >> 4, l16 = lane & 15;
#pragma unroll
  for (int mi = 0; mi < 4; ++mi)
#pragma unroll
    for (int ni = 0; ni < 4; ++ni)
#pragma unroll
      for (int reg = 0; reg < 4; ++reg) {
        int grow = bm * 128 + wr * 64 + mi * 16 + g * 4 + reg;
        int gcol = bn * 128 + wc * 64 + ni * 16 + l16;
        v[(size_t)grow * 512 + gcol] = acc[mi][ni][reg] + bvec[gcol];
      }
}

// ---------------- row L2-normalize: z = v / max(||v||, eps) as bf16 ----
__global__ __launch_bounds__(256) void normalize_rows(
    const float* __restrict__ v, __hip_bfloat16* __restrict__ z) {
  int r = blockIdx.x;
  int tid = threadIdx.x;
  const float* vr = v + (size_t)r * 512;
  float2 xv = *(const float2*)(vr + tid * 2);
  float s = xv.x * xv.x + xv.y * xv.y;
#pragma unroll
  for (int m = 1; m < 64; m <<= 1) s += __shfl_xor(s, m);
  __shared__ float ws4[4];
  int w = tid >> 6, lane = tid & 63;
  if (lane == 0) ws4[w] = s;
  __syncthreads();
  float tot = ws4[0] + ws4[1] + ws4[2] + ws4[3];
  float inv = 1.0f / fmaxf(sqrtf(tot), 1e-12f);
  unsigned int o = (unsigned int)f2bf(xv.x * inv) | ((unsigned int)f2bf(xv.y * inv) << 16);
  *(unsigned int*)(z + (size_t)r * 512 + tid * 2) = o;
}

// ---------------- fused sim GEMM + exp row-sums + pos/self capture ----
__global__ __launch_bounds__(256) void sim_fused(
    const __hip_bfloat16* __restrict__ z, float* __restrict__ partial,
    float* __restrict__ possim, float* __restrict__ selfsim) {
  __shared__ __align__(16) __hip_bfloat16 As[4096], Bs[4096];
  __shared__ float wsum[2][128];
  int bj = blockIdx.x, bi = blockIdx.y;
  int tid = threadIdx.x;
  f32x4 acc[4][4];
#pragma unroll
  for (int i = 0; i < 4; ++i)
#pragma unroll
    for (int j = 0; j < 4; ++j) acc[i][j] = (f32x4){0.f, 0.f, 0.f, 0.f};
  gemm_tile_128<512>(z + (size_t)bi * 128 * 512, z + (size_t)bj * 128 * 512,
                     512, As, Bs, acc, tid);
  int w = tid >> 6, lane = tid & 63, wr = w >> 1, wc = w & 1, g = lane >> 4, l16 = lane & 15;
  // pos (bj = bi +- 48) and self (bj = bi) live on local tile diagonals
  bool posj  = (bj == bi + 48) || (bj + 48 == bi);
  bool diagj = (bj == bi);
  if ((posj || diagj) && (wr == wc)) {
#pragma unroll
    for (int mi = 0; mi < 4; ++mi)
#pragma unroll
      for (int reg = 0; reg < 4; ++reg)
        if (l16 == g * 4 + reg) {
          int row_local = wr * 64 + mi * 16 + g * 4 + reg;
          float sv = acc[mi][mi][reg];
          if (posj) possim[bi * 128 + row_local] = sv;
          else      selfsim[bi * 128 + row_local] = sv;
        }
  }
  // exp + per-row partial sums (deterministic: unique (bj,row) writer)
  float lsum[4][4];
#pragma unroll
  for (int mi = 0; mi < 4; ++mi)
#pragma unroll
    for (int reg = 0; reg < 4; ++reg) {
      float s = 0.f;
#pragma unroll
      for (int ni = 0; ni < 4; ++ni)
        s += exp2f(acc[mi][ni][reg] * EXP_SCALE);
      lsum[mi][reg] = s;
    }
#pragma unroll
  for (int m = 1; m < 16; m <<= 1)
#pragma unroll
    for (int mi = 0; mi < 4; ++mi)
#pragma unroll
      for (int reg = 0; reg < 4; ++reg)
        lsum[mi][reg] += __shfl_xor(lsum[mi][reg], m);
  if (l16 == 0) {
#pragma unroll
    for (int mi = 0; mi < 4; ++mi)
#pragma unroll
      for (int reg = 0; reg < 4; ++reg)
        wsum[wc][wr * 64 + mi * 16 + g * 4 + reg] = lsum[mi][reg];
  }
  __syncthreads();
  if (tid < 128)
    partial[(size_t)bj * NROWS + bi * 128 + tid] = wsum[0][tid] + wsum[1][tid];
}

// ---------------- per-row term ----------------
__global__ __launch_bounds__(256) void finalize_terms(
    const float* __restrict__ partial, const float* __restrict__ possim,
    const float* __restrict__ selfsim, float* __restrict__ terms) {
  int i = blockIdx.x * 256 + threadIdx.x;
  float s = 0.f;
  for (int bj = 0; bj < NTILE; ++bj) s += partial[(size_t)bj * NROWS + i];
  float denom = s - exp2f(selfsim[i] * EXP_SCALE);
  terms[i] = -2.0f * possim[i] + logf(denom);
}

// ---------------- deterministic single-block sum ----------------
__global__ __launch_bounds__(256) void finalize_sum(
    const float* __restrict__ terms, float* __restrict__ out) {
  int tid = threadIdx.x;
  float s = 0.f;
  for (int i = tid; i < NROWS; i += 256) s += terms[i];
#pragma unroll
  for (int m = 1; m < 64; m <<= 1) s += __shfl_xor(s, m);
  __shared__ float ws4[4];
  int w = tid >> 6, lane = tid & 63;
  if (lane == 0) ws4[w] = s;
  __syncthreads();
  if (tid == 0) out[0] = (ws4[0] + ws4[1] + ws4[2] + ws4[3]) / 12288.0f;
}

extern "C" void kernel_launch(void* const* d_in, const int* in_sizes, int n_in,
                              void* d_out, int out_size, void* d_ws, size_t ws_size,
                              hipStream_t stream) {
  const float* f_seq = (const float*)d_in[0];
  const float* f_spa = (const float*)d_in[1];
  const float* W     = (const float*)d_in[2];
  const float* b     = (const float*)d_in[3];
  char* ws = (char*)d_ws;
  // layout (aliased): [0,25165824) Abig bf16; after proj_gemm the region is
  // reused for z(bf16,12582912) + partial(4718592) + possim/selfsim/terms.
  __hip_bfloat16* Abig = (__hip_bfloat16*)ws;
  __hip_bfloat16* Wt   = (__hip_bfloat16*)(ws + 25165824);   // 1048576 B
  float* v             = (float*)(ws + 26214400);            // 25165824 B
  __hip_bfloat16* z    = (__hip_bfloat16*)ws;                // alias over Abig
  float* partial       = (float*)(ws + 12582912);            // 96*12288*4
  float* possim        = (float*)(ws + 17301504);
  float* selfsim       = (float*)(ws + 17350656);
  float* terms         = (float*)(ws + 17399808);
  float* out           = (float*)d_out;

  gather_convert<<<dim3(12288), dim3(256), 0, stream>>>(f_seq, f_spa, Abig);
  wt_convert<<<dim3(512), dim3(256), 0, stream>>>(W, Wt);
  proj_gemm<<<dim3(4, 96), dim3(256), 0, stream>>>(Abig, Wt, b, v);
  normalize_rows<<<dim3(12288), dim3(256), 0, stream>>>(v, z);
  sim_fused<<<dim3(96, 96), dim3(256), 0, stream>>>(z, partial, possim, selfsim);
  finalize_terms<<<dim3(48), dim3(256), 0, stream>>>(partial, possim, selfsim, terms);
  finalize_sum<<<dim3(1), dim3(256), 0, stream>>>(terms, out);
}

// Round 2
// 273.078 us; speedup vs baseline: 1.1353x; 1.1353x over previous
//
#include <hip/hip_runtime.h>
#include <hip/hip_bf16.h>
#include <cstdint>
#include <cstddef>

#define B_DIM 2048
#define D_DIM 512
#define NROWS 12288        // 6B rows of z
#define HALF  6144         // 3B
#define NTILE 96           // NROWS/128
#define NPAIR 4656         // NTILE*(NTILE+1)/2
#define EXP_SCALE 2.8853900817779268f   // log2(e)/TEMP, TEMP=0.5

typedef __attribute__((ext_vector_type(8))) __bf16 bf16x8;
typedef __attribute__((ext_vector_type(4))) float f32x4;

__device__ __forceinline__ unsigned short f2bf(float x) {
  __hip_bfloat16 h = __float2bfloat16(x);
  return *reinterpret_cast<unsigned short*>(&h);
}

__device__ __forceinline__ void gload_lds16(const void* g, void* l) {
  __builtin_amdgcn_global_load_lds(
      (const __attribute__((address_space(1))) unsigned int*)g,
      (__attribute__((address_space(3))) unsigned int*)l,
      16, 0, 0);
}

// ---------------- gather f -> Abig bf16 [12288 x 1024] ----------------
__global__ __launch_bounds__(256) void gather_convert(
    const float* __restrict__ f_seq, const float* __restrict__ f_spa,
    __hip_bfloat16* __restrict__ Abig) {
  int t = blockIdx.x * 256 + threadIdx.x;   // one thread per 4 elems
  int r = t >> 8;
  int k = (t & 255) << 2;
  const float* f = (r < HALF) ? f_spa : f_seq;
  int rr = (r < HALF) ? r : r - HALF;
  int p = rr >> 11;           // /2048
  int i = rr & 2047;
  int sel = (p == 2) ? 3 : p;
  const float* src;
  if (k < D_DIM) src = f + ((size_t)i * 4 + sel) * D_DIM + k;
  else           src = f + ((size_t)i * 4 + 2) * D_DIM + (k - D_DIM);
  float4 xv = *(const float4*)src;
  uint2 o;
  o.x = (unsigned int)f2bf(xv.x) | ((unsigned int)f2bf(xv.y) << 16);
  o.y = (unsigned int)f2bf(xv.z) | ((unsigned int)f2bf(xv.w) << 16);
  *(uint2*)(Abig + (size_t)r * 1024 + k) = o;
}

// ---------------- W [1024x512] -> Wt bf16 [512 x 1024] (transposed) ----
__global__ __launch_bounds__(256) void wt_convert(
    const float* __restrict__ W, __hip_bfloat16* __restrict__ Wt) {
  int t = blockIdx.x * 256 + threadIdx.x;   // per 4 elems of Wt
  int n = t >> 8;
  int k = (t & 255) << 2;
  float x0 = W[(size_t)(k + 0) * 512 + n];
  float x1 = W[(size_t)(k + 1) * 512 + n];
  float x2 = W[(size_t)(k + 2) * 512 + n];
  float x3 = W[(size_t)(k + 3) * 512 + n];
  uint2 o;
  o.x = (unsigned int)f2bf(x0) | ((unsigned int)f2bf(x1) << 16);
  o.y = (unsigned int)f2bf(x2) | ((unsigned int)f2bf(x3) << 16);
  *(uint2*)(Wt + (size_t)n * 1024 + k) = o;
}

// ---------------- shared 128x128 MFMA tile core (C = A @ B^T form) ----
// LDS layout: [chunk g 0..3][row 0..127][8 bf16] (2048 B per chunk section).
// global_load_lds dest is linear per wave; source pre-permuted to match.
// Read: 16 consecutive lanes hit 256 contiguous bytes -> conflict-free.
template<int STRIDE>
__device__ __forceinline__ void gemm_tile_128(
    const __hip_bfloat16* Arows, const __hip_bfloat16* Brows, int K,
    __hip_bfloat16* As, __hip_bfloat16* Bs, f32x4 acc[4][4], int tid) {
  int w = tid >> 6, lane = tid & 63;
  int wr = w >> 1, wc = w & 1;
  int g = lane >> 4, l16 = lane & 15;
  int row0 = tid & 127, ch0 = tid >> 7;       // granule tid      -> chunk 0/1
  // granule 256+tid -> same row, chunk 2/3
  for (int kt = 0; kt < K; kt += 32) {
    gload_lds16(Arows + (size_t)row0 * STRIDE + kt + ch0 * 8, As + w * 512);
    gload_lds16(Arows + (size_t)row0 * STRIDE + kt + (ch0 + 2) * 8, As + 2048 + w * 512);
    gload_lds16(Brows + (size_t)row0 * STRIDE + kt + ch0 * 8, Bs + w * 512);
    gload_lds16(Brows + (size_t)row0 * STRIDE + kt + (ch0 + 2) * 8, Bs + 2048 + w * 512);
    __syncthreads();
    bf16x8 af[4], bfr[4];
#pragma unroll
    for (int mi = 0; mi < 4; ++mi)
      af[mi] = *(const bf16x8*)(As + g * 1024 + (wr * 64 + mi * 16 + l16) * 8);
#pragma unroll
    for (int ni = 0; ni < 4; ++ni)
      bfr[ni] = *(const bf16x8*)(Bs + g * 1024 + (wc * 64 + ni * 16 + l16) * 8);
#pragma unroll
    for (int mi = 0; mi < 4; ++mi)
#pragma unroll
      for (int ni = 0; ni < 4; ++ni)
        acc[mi][ni] = __builtin_amdgcn_mfma_f32_16x16x32_bf16(af[mi], bfr[ni], acc[mi][ni], 0, 0, 0);
    __syncthreads();
  }
}

// ---------------- projection GEMM: v = Abig @ Wt^T + b  (fp32 out) ----
__global__ __launch_bounds__(256) void proj_gemm(
    const __hip_bfloat16* __restrict__ Abig, const __hip_bfloat16* __restrict__ Wt,
    const float* __restrict__ bvec, float* __restrict__ v) {
  __shared__ __align__(16) __hip_bfloat16 As[4096], Bs[4096];
  int bn = blockIdx.x, bm = blockIdx.y;
  f32x4 acc[4][4];
#pragma unroll
  for (int i = 0; i < 4; ++i)
#pragma unroll
    for (int j = 0; j < 4; ++j) acc[i][j] = (f32x4){0.f, 0.f, 0.f, 0.f};
  int tid = threadIdx.x;
  gemm_tile_128<1024>(Abig + (size_t)bm * 128 * 1024, Wt + (size_t)bn * 128 * 1024,
                      1024, As, Bs, acc, tid);
  int w = tid >> 6, lane = tid & 63, wr = w >> 1, wc = w & 1, g = lane >> 4, l16 = lane & 15;
#pragma unroll
  for (int mi = 0; mi < 4; ++mi)
#pragma unroll
    for (int ni = 0; ni < 4; ++ni)
#pragma unroll
      for (int reg = 0; reg < 4; ++reg) {
        int grow = bm * 128 + wr * 64 + mi * 16 + g * 4 + reg;
        int gcol = bn * 128 + wc * 64 + ni * 16 + l16;
        v[(size_t)grow * 512 + gcol] = acc[mi][ni][reg] + bvec[gcol];
      }
}

// ---------------- row L2-normalize: z = v / max(||v||, eps) as bf16 ----
__global__ __launch_bounds__(256) void normalize_rows(
    const float* __restrict__ v, __hip_bfloat16* __restrict__ z) {
  int r = blockIdx.x;
  int tid = threadIdx.x;
  const float* vr = v + (size_t)r * 512;
  float2 xv = *(const float2*)(vr + tid * 2);
  float s = xv.x * xv.x + xv.y * xv.y;
#pragma unroll
  for (int m = 1; m < 64; m <<= 1) s += __shfl_xor(s, m);
  __shared__ float ws4[4];
  int w = tid >> 6, lane = tid & 63;
  if (lane == 0) ws4[w] = s;
  __syncthreads();
  float tot = ws4[0] + ws4[1] + ws4[2] + ws4[3];
  float inv = 1.0f / fmaxf(sqrtf(tot), 1e-12f);
  unsigned int o = (unsigned int)f2bf(xv.x * inv) | ((unsigned int)f2bf(xv.y * inv) << 16);
  *(unsigned int*)(z + (size_t)r * 512 + tid * 2) = o;
}

// ---- fused symmetric sim GEMM: tiles bi<=bj, exp row+col sums --------
__global__ __launch_bounds__(256) void sim_fused_sym(
    const __hip_bfloat16* __restrict__ z, float* __restrict__ partial,
    float* __restrict__ possim, float* __restrict__ selfsim) {
  __shared__ __align__(16) __hip_bfloat16 As[4096], Bs[4096];
  __shared__ float wsum[2][128];
  __shared__ float csum[2][128];
  int t = blockIdx.x;
  // map t -> (bi, bj), bi<=bj<96; off(bi) = bi*(193-bi)/2
  int bi = (int)((193.0f - sqrtf(37249.0f - 8.0f * (float)t)) * 0.5f);
  if (bi < 0) bi = 0;
  if (bi > 95) bi = 95;
  while (bi > 0 && (bi * (193 - bi)) / 2 > t) --bi;
  while (bi < 95 && ((bi + 1) * (192 - bi)) / 2 <= t) ++bi;
  int bj = bi + (t - (bi * (193 - bi)) / 2);
  int tid = threadIdx.x;
  f32x4 acc[4][4];
#pragma unroll
  for (int i = 0; i < 4; ++i)
#pragma unroll
    for (int j = 0; j < 4; ++j) acc[i][j] = (f32x4){0.f, 0.f, 0.f, 0.f};
  gemm_tile_128<512>(z + (size_t)bi * 128 * 512, z + (size_t)bj * 128 * 512,
                     512, As, Bs, acc, tid);
  int w = tid >> 6, lane = tid & 63, wr = w >> 1, wc = w & 1, g = lane >> 4, l16 = lane & 15;
  bool diag = (bi == bj);
  bool posT = (bj == bi + 48);
  // capture diagonal values BEFORE exp-ing acc in place
  if ((diag || posT) && (wr == wc)) {
#pragma unroll
    for (int mi = 0; mi < 4; ++mi)
#pragma unroll
      for (int reg = 0; reg < 4; ++reg)
        if (l16 == g * 4 + reg) {
          int rl = wr * 64 + mi * 16 + g * 4 + reg;
          float sv = acc[mi][mi][reg];
          if (diag) selfsim[bi * 128 + rl] = sv;
          else      possim[bi * 128 + rl] = sv;   // bi < 48 here
        }
  }
  // exp in place
#pragma unroll
  for (int mi = 0; mi < 4; ++mi)
#pragma unroll
    for (int ni = 0; ni < 4; ++ni)
#pragma unroll
      for (int reg = 0; reg < 4; ++reg)
        acc[mi][ni][reg] = exp2f(acc[mi][ni][reg] * EXP_SCALE);
  // row sums (rows of bi-tile): sum over ni in-thread, then l16 reduce
  float rs[4][4];
#pragma unroll
  for (int mi = 0; mi < 4; ++mi)
#pragma unroll
    for (int reg = 0; reg < 4; ++reg) {
      float s = acc[mi][0][reg] + acc[mi][1][reg] + acc[mi][2][reg] + acc[mi][3][reg];
      rs[mi][reg] = s;
    }
#pragma unroll
  for (int m = 1; m < 16; m <<= 1)
#pragma unroll
    for (int mi = 0; mi < 4; ++mi)
#pragma unroll
      for (int reg = 0; reg < 4; ++reg)
        rs[mi][reg] += __shfl_xor(rs[mi][reg], m);
  if (l16 == 0) {
#pragma unroll
    for (int mi = 0; mi < 4; ++mi)
#pragma unroll
      for (int reg = 0; reg < 4; ++reg)
        wsum[wc][wr * 64 + mi * 16 + g * 4 + reg] = rs[mi][reg];
  }
  // col sums (rows of bj-tile): sum over mi,reg in-thread, then g reduce
  float cs[4];
#pragma unroll
  for (int ni = 0; ni < 4; ++ni) {
    float s = 0.f;
#pragma unroll
    for (int mi = 0; mi < 4; ++mi)
#pragma unroll
      for (int reg = 0; reg < 4; ++reg)
        s += acc[mi][ni][reg];
    cs[ni] = s;
  }
#pragma unroll
  for (int ni = 0; ni < 4; ++ni) {
    cs[ni] += __shfl_xor(cs[ni], 16);
    cs[ni] += __shfl_xor(cs[ni], 32);
  }
  if (g == 0) {
#pragma unroll
    for (int ni = 0; ni < 4; ++ni)
      csum[wr][wc * 64 + ni * 16 + l16] = cs[ni];
  }
  __syncthreads();
  if (tid < 128) {
    partial[(size_t)bj * NROWS + bi * 128 + tid] = wsum[0][tid] + wsum[1][tid];
    if (!diag)
      partial[(size_t)bi * NROWS + bj * 128 + tid] = csum[0][tid] + csum[1][tid];
  }
}

// ---------------- per-row term ----------------
__global__ __launch_bounds__(256) void finalize_terms(
    const float* __restrict__ partial, const float* __restrict__ possim,
    const float* __restrict__ selfsim, float* __restrict__ terms) {
  int i = blockIdx.x * 256 + threadIdx.x;
  float s = 0.f;
  for (int bj = 0; bj < NTILE; ++bj) s += partial[(size_t)bj * NROWS + i];
  float denom = s - exp2f(selfsim[i] * EXP_SCALE);
  float pos = possim[(i < HALF) ? i : (i - HALF)];
  terms[i] = -2.0f * pos + logf(denom);
}

// ---------------- deterministic single-block sum ----------------
__global__ __launch_bounds__(256) void finalize_sum(
    const float* __restrict__ terms, float* __restrict__ out) {
  int tid = threadIdx.x;
  float s = 0.f;
  for (int i = tid; i < NROWS; i += 256) s += terms[i];
#pragma unroll
  for (int m = 1; m < 64; m <<= 1) s += __shfl_xor(s, m);
  __shared__ float ws4[4];
  int w = tid >> 6, lane = tid & 63;
  if (lane == 0) ws4[w] = s;
  __syncthreads();
  if (tid == 0) out[0] = (ws4[0] + ws4[1] + ws4[2] + ws4[3]) / 12288.0f;
}

extern "C" void kernel_launch(void* const* d_in, const int* in_sizes, int n_in,
                              void* d_out, int out_size, void* d_ws, size_t ws_size,
                              hipStream_t stream) {
  const float* f_seq = (const float*)d_in[0];
  const float* f_spa = (const float*)d_in[1];
  const float* W     = (const float*)d_in[2];
  const float* b     = (const float*)d_in[3];
  char* ws = (char*)d_ws;
  __hip_bfloat16* Abig = (__hip_bfloat16*)ws;                // 25165824 B
  __hip_bfloat16* Wt   = (__hip_bfloat16*)(ws + 25165824);   // 1048576 B
  float* v             = (float*)(ws + 26214400);            // 25165824 B
  __hip_bfloat16* z    = (__hip_bfloat16*)ws;                // alias over dead Abig
  float* partial       = (float*)(ws + 12582912);            // 96*12288*4 = 4718592
  float* possim        = (float*)(ws + 17301504);            // 6144*4
  float* selfsim       = (float*)(ws + 17326080);            // 12288*4
  float* terms         = (float*)(ws + 17375232);            // 12288*4
  float* out           = (float*)d_out;

  gather_convert<<<dim3(12288), dim3(256), 0, stream>>>(f_seq, f_spa, Abig);
  wt_convert<<<dim3(512), dim3(256), 0, stream>>>(W, Wt);
  proj_gemm<<<dim3(4, 96), dim3(256), 0, stream>>>(Abig, Wt, b, v);
  normalize_rows<<<dim3(12288), dim3(256), 0, stream>>>(v, z);
  sim_fused_sym<<<dim3(NPAIR), dim3(256), 0, stream>>>(z, partial, possim, selfsim);
  finalize_terms<<<dim3(48), dim3(256), 0, stream>>>(partial, possim, selfsim, terms);
  finalize_sum<<<dim3(1), dim3(256), 0, stream>>>(terms, out);
}